// Round 7
// baseline (31431.482 us; speedup 1.0000x reference)
//
#include <hip/hip_runtime.h>
#include <math.h>

#define BM 128
#define BN 128
#define BK 16
#define LDP 132   /* padded leading dim for [BK][...] LDS tiles */
#define TC 128    /* t-chunk */
#define NC (TC * 128) /* rows per chunk = 16384 */

__device__ __forceinline__ float sigf(float x) { return 1.0f / (1.0f + expf(-x)); }

// C[n,m] = sum_k A[n,k]*B[m,k] (+bias[m]).  A is [N,K] row-major (K contiguous).
// B_KM=false: B is [M,K] row-major -> staged transposed.
// B_KM=true : B is [K,M] (M contiguous, row stride ldb) -> staged directly.
template <bool B_KM>
__global__ __launch_bounds__(256, 2) void gemm_nt(
    const float* __restrict__ A, int lda, long sAz,
    const float* __restrict__ B, int ldb, long sBz,
    float* __restrict__ C, int ldc, long sCz,
    int K, const float* __restrict__ bias)
{
    __shared__ alignas(16) float As[2][BK][LDP];
    __shared__ alignas(16) float Bs[2][BK][LDP];
    const int t = threadIdx.x;
    const long z = blockIdx.z;
    A += z * sAz;
    B += z * sBz;
    C += z * sCz;
    const int n0 = blockIdx.x * BM;
    const int m0 = blockIdx.y * BN;
    const int tx = t & 15, ty = t >> 4;
    const int kq = t & 3;
    const int rA = t >> 2;
    const int kb = t >> 5;
    const int cb = t & 31;

    float4 ar[2], br[2];

    auto load_regs = [&](int kt) {
        const int kbase = kt * BK;
        ar[0] = *(const float4*)(A + (long)(n0 + rA) * lda + kbase + kq * 4);
        ar[1] = *(const float4*)(A + (long)(n0 + rA + 64) * lda + kbase + kq * 4);
        if (!B_KM) {
            br[0] = *(const float4*)(B + (long)(m0 + rA) * ldb + kbase + kq * 4);
            br[1] = *(const float4*)(B + (long)(m0 + rA + 64) * ldb + kbase + kq * 4);
        } else {
            br[0] = *(const float4*)(B + (long)(kbase + kb) * ldb + m0 + cb * 4);
            br[1] = *(const float4*)(B + (long)(kbase + kb + 8) * ldb + m0 + cb * 4);
        }
    };
    auto store_lds = [&](int buf) {
        As[buf][kq * 4 + 0][rA] = ar[0].x;
        As[buf][kq * 4 + 1][rA] = ar[0].y;
        As[buf][kq * 4 + 2][rA] = ar[0].z;
        As[buf][kq * 4 + 3][rA] = ar[0].w;
        As[buf][kq * 4 + 0][rA + 64] = ar[1].x;
        As[buf][kq * 4 + 1][rA + 64] = ar[1].y;
        As[buf][kq * 4 + 2][rA + 64] = ar[1].z;
        As[buf][kq * 4 + 3][rA + 64] = ar[1].w;
        if (!B_KM) {
            Bs[buf][kq * 4 + 0][rA] = br[0].x;
            Bs[buf][kq * 4 + 1][rA] = br[0].y;
            Bs[buf][kq * 4 + 2][rA] = br[0].z;
            Bs[buf][kq * 4 + 3][rA] = br[0].w;
            Bs[buf][kq * 4 + 0][rA + 64] = br[1].x;
            Bs[buf][kq * 4 + 1][rA + 64] = br[1].y;
            Bs[buf][kq * 4 + 2][rA + 64] = br[1].z;
            Bs[buf][kq * 4 + 3][rA + 64] = br[1].w;
        } else {
            *(float4*)&Bs[buf][kb][cb * 4] = br[0];
            *(float4*)&Bs[buf][kb + 8][cb * 4] = br[1];
        }
    };

    float acc[8][8];
#pragma unroll
    for (int i = 0; i < 8; i++)
#pragma unroll
        for (int j = 0; j < 8; j++) acc[i][j] = 0.f;

    load_regs(0);
    store_lds(0);
    const int nkt = K / BK;
    for (int kt = 0; kt < nkt; ++kt) {
        __syncthreads();
        const int cur = kt & 1;
        if (kt + 1 < nkt) load_regs(kt + 1);
#pragma unroll
        for (int k = 0; k < BK; ++k) {
            float4 a0 = *(const float4*)&As[cur][k][ty * 4];
            float4 a1 = *(const float4*)&As[cur][k][ty * 4 + 64];
            float4 b0 = *(const float4*)&Bs[cur][k][tx * 4];
            float4 b1 = *(const float4*)&Bs[cur][k][tx * 4 + 64];
            float av[8] = {a0.x, a0.y, a0.z, a0.w, a1.x, a1.y, a1.z, a1.w};
            float bv[8] = {b0.x, b0.y, b0.z, b0.w, b1.x, b1.y, b1.z, b1.w};
#pragma unroll
            for (int i = 0; i < 8; i++)
#pragma unroll
                for (int j = 0; j < 8; j++)
                    acc[i][j] = fmaf(av[i], bv[j], acc[i][j]);
        }
        if (kt + 1 < nkt) store_lds((kt + 1) & 1);
    }

    float bv0[8];
#pragma unroll
    for (int j = 0; j < 8; j++)
        bv0[j] = bias ? bias[m0 + tx * 4 + (j & 3) + (j >> 2) * 64] : 0.f;

#pragma unroll
    for (int i = 0; i < 8; i++) {
        const long row = n0 + ty * 4 + (i & 3) + (i >> 2) * 64;
        float* cp = C + row * (long)ldc + m0;
        float4 v;
        v.x = acc[i][0] + bv0[0];
        v.y = acc[i][1] + bv0[1];
        v.z = acc[i][2] + bv0[2];
        v.w = acc[i][3] + bv0[3];
        *(float4*)(cp + tx * 4) = v;
        v.x = acc[i][4] + bv0[4];
        v.y = acc[i][5] + bv0[5];
        v.z = acc[i][6] + bv0[6];
        v.w = acc[i][7] + bv0[7];
        *(float4*)(cp + tx * 4 + 64) = v;
    }
}

// Fused gates GEMM + LSTM cell.  A = [Ah | Ar] each [NC,256] (K=512 split at 256).
// W is gate-permuted [1024,512] (row 4d+g = gate g of channel d), bp permuted bias.
// Epilogue: c_new = sig(f)*c_old + sig(i)*tanh(g); h = sig(o)*tanh(c_new).
// h -> Hout[n,ch], c_new -> Cbuf[n,ch].  Each (n,ch) touched by exactly one thread.
template <bool STEP0>
__global__ __launch_bounds__(256, 2) void gemm_gates(
    const float* __restrict__ Ah, const float* __restrict__ Ar,
    const float* __restrict__ W, const float* __restrict__ bp,
    float* __restrict__ Hout, float* __restrict__ Cbuf)
{
    __shared__ alignas(16) float As[2][BK][LDP];
    __shared__ alignas(16) float Bs[2][BK][LDP];
    const int t = threadIdx.x;
    const int n0 = blockIdx.x * BM;
    const int m0 = blockIdx.y * BN;
    const int tx = t & 15, ty = t >> 4;
    const int kq = t & 3;
    const int rA = t >> 2;

    float4 ar[2], br[2];

    auto load_regs = [&](int kt) {
        const int kbase = kt * BK;
        const float* Ak = (kbase < 256) ? Ah : Ar;
        const int kc = (kbase & 255) + kq * 4;
        ar[0] = *(const float4*)(Ak + (long)(n0 + rA) * 256 + kc);
        ar[1] = *(const float4*)(Ak + (long)(n0 + rA + 64) * 256 + kc);
        br[0] = *(const float4*)(W + (long)(m0 + rA) * 512 + kbase + kq * 4);
        br[1] = *(const float4*)(W + (long)(m0 + rA + 64) * 512 + kbase + kq * 4);
    };
    auto store_lds = [&](int buf) {
        As[buf][kq * 4 + 0][rA] = ar[0].x;
        As[buf][kq * 4 + 1][rA] = ar[0].y;
        As[buf][kq * 4 + 2][rA] = ar[0].z;
        As[buf][kq * 4 + 3][rA] = ar[0].w;
        As[buf][kq * 4 + 0][rA + 64] = ar[1].x;
        As[buf][kq * 4 + 1][rA + 64] = ar[1].y;
        As[buf][kq * 4 + 2][rA + 64] = ar[1].z;
        As[buf][kq * 4 + 3][rA + 64] = ar[1].w;
        Bs[buf][kq * 4 + 0][rA] = br[0].x;
        Bs[buf][kq * 4 + 1][rA] = br[0].y;
        Bs[buf][kq * 4 + 2][rA] = br[0].z;
        Bs[buf][kq * 4 + 3][rA] = br[0].w;
        Bs[buf][kq * 4 + 0][rA + 64] = br[1].x;
        Bs[buf][kq * 4 + 1][rA + 64] = br[1].y;
        Bs[buf][kq * 4 + 2][rA + 64] = br[1].z;
        Bs[buf][kq * 4 + 3][rA + 64] = br[1].w;
    };

    float acc[8][8];
#pragma unroll
    for (int i = 0; i < 8; i++)
#pragma unroll
        for (int j = 0; j < 8; j++) acc[i][j] = 0.f;

    load_regs(0);
    store_lds(0);
    const int nkt = 512 / BK;
    for (int kt = 0; kt < nkt; ++kt) {
        __syncthreads();
        const int cur = kt & 1;
        if (kt + 1 < nkt) load_regs(kt + 1);
#pragma unroll
        for (int k = 0; k < BK; ++k) {
            float4 a0 = *(const float4*)&As[cur][k][ty * 4];
            float4 a1 = *(const float4*)&As[cur][k][ty * 4 + 64];
            float4 b0 = *(const float4*)&Bs[cur][k][tx * 4];
            float4 b1 = *(const float4*)&Bs[cur][k][tx * 4 + 64];
            float av[8] = {a0.x, a0.y, a0.z, a0.w, a1.x, a1.y, a1.z, a1.w};
            float bv[8] = {b0.x, b0.y, b0.z, b0.w, b1.x, b1.y, b1.z, b1.w};
#pragma unroll
            for (int i = 0; i < 8; i++)
#pragma unroll
                for (int j = 0; j < 8; j++)
                    acc[i][j] = fmaf(av[i], bv[j], acc[i][j]);
        }
        if (kt + 1 < nkt) store_lds((kt + 1) & 1);
    }

    float bv0[8];
#pragma unroll
    for (int j = 0; j < 8; j++)
        bv0[j] = bp[m0 + tx * 4 + (j & 3) + (j >> 2) * 64];

    const int ch0 = (m0 + tx * 4) >> 2; // channel of acc[.][0..3]; +16 for acc[.][4..7]
#pragma unroll
    for (int i = 0; i < 8; i++) {
        const long n = n0 + ty * 4 + (i & 3) + (i >> 2) * 64;
#pragma unroll
        for (int g2 = 0; g2 < 2; g2++) {
            const float ii = acc[i][g2 * 4 + 0] + bv0[g2 * 4 + 0];
            const float ff = acc[i][g2 * 4 + 1] + bv0[g2 * 4 + 1];
            const float gg = acc[i][g2 * 4 + 2] + bv0[g2 * 4 + 2];
            const float oo = acc[i][g2 * 4 + 3] + bv0[g2 * 4 + 3];
            const int ch = ch0 + 16 * g2;
            float co = STEP0 ? 0.f : Cbuf[n * 256 + ch];
            const float cn = sigf(ff) * co + sigf(ii) * tanhf(gg);
            const float hh = sigf(oo) * tanhf(cn);
            Cbuf[n * 256 + ch] = cn;
            Hout[n * 256 + ch] = hh;
        }
    }
}

// Row softmax over E[b][tc][u] (chunk rows = b*TC+tc), u masked to u<len[b].
__global__ __launch_bounds__(256) void softmax_kernel(
    float* __restrict__ E, const int* __restrict__ lens)
{
    const int row = blockIdx.x * 4 + (threadIdx.x >> 6); // row = b*TC + tc
    const int lane = threadIdx.x & 63;
    const int b = row >> 7; // TC = 128
    const int len = lens[b];
    float* e = E + (long)row * 512;
    float4 v0 = *(const float4*)(e + lane * 4);       // u in [0,256): always valid (len>=256)
    float4 v1 = *(const float4*)(e + 256 + lane * 4); // u in [256,512): mask
    const int u1 = 256 + lane * 4;
    float m = fmaxf(fmaxf(v0.x, v0.y), fmaxf(v0.z, v0.w));
    if (u1 + 0 < len) m = fmaxf(m, v1.x);
    if (u1 + 1 < len) m = fmaxf(m, v1.y);
    if (u1 + 2 < len) m = fmaxf(m, v1.z);
    if (u1 + 3 < len) m = fmaxf(m, v1.w);
#pragma unroll
    for (int off = 32; off; off >>= 1) m = fmaxf(m, __shfl_xor(m, off));
    float4 e0, e1;
    e0.x = expf(v0.x - m);
    e0.y = expf(v0.y - m);
    e0.z = expf(v0.z - m);
    e0.w = expf(v0.w - m);
    e1.x = (u1 + 0 < len) ? expf(v1.x - m) : 0.f;
    e1.y = (u1 + 1 < len) ? expf(v1.y - m) : 0.f;
    e1.z = (u1 + 2 < len) ? expf(v1.z - m) : 0.f;
    e1.w = (u1 + 3 < len) ? expf(v1.w - m) : 0.f;
    float s = e0.x + e0.y + e0.z + e0.w + e1.x + e1.y + e1.z + e1.w;
#pragma unroll
    for (int off = 32; off; off >>= 1) s += __shfl_xor(s, off);
    const float inv = 1.f / s;
    e0.x *= inv; e0.y *= inv; e0.z *= inv; e0.w *= inv;
    e1.x *= inv; e1.y *= inv; e1.z *= inv; e1.w *= inv;
    *(float4*)(e + lane * 4) = e0;
    *(float4*)(e + 256 + lane * 4) = e1;
}

// Partial logits for one bank.  feat = relu([QH|QR]) [NC,512]; ow slice [7, 512].
// BANK==0: Plog[n][c] = dot.  BANK==1: finalize log_softmax(Plog+dot+ob) and
// scatter valid rows conversation-major.
template <int BANK>
__global__ __launch_bounds__(256) void plog_kernel(
    const float* __restrict__ QH, const float* __restrict__ QR,
    const float* __restrict__ ow, const float* __restrict__ ob,
    const int* __restrict__ lens, const int* __restrict__ offs, int t0,
    float* __restrict__ Plog, float* __restrict__ out)
{
    __shared__ alignas(16) float wsh[7][512];
    for (int i = threadIdx.x; i < 7 * 512; i += 256)
        wsh[i >> 9][i & 511] = ow[(i >> 9) * 1024 + BANK * 512 + (i & 511)];
    __syncthreads();
    const int n = blockIdx.x * 4 + (threadIdx.x >> 6); // chunk row = tc*128 + b
    const int lane = threadIdx.x & 63;
    float4 h4 = *(const float4*)(QH + (long)n * 256 + lane * 4);
    float4 r4 = *(const float4*)(QR + (long)n * 256 + lane * 4);
    h4.x = fmaxf(h4.x, 0.f); h4.y = fmaxf(h4.y, 0.f); h4.z = fmaxf(h4.z, 0.f); h4.w = fmaxf(h4.w, 0.f);
    r4.x = fmaxf(r4.x, 0.f); r4.y = fmaxf(r4.y, 0.f); r4.z = fmaxf(r4.z, 0.f); r4.w = fmaxf(r4.w, 0.f);
    float part[7];
#pragma unroll
    for (int c = 0; c < 7; c++) {
        float4 wa = *(const float4*)&wsh[c][lane * 4];
        float4 wb = *(const float4*)&wsh[c][256 + lane * 4];
        part[c] = h4.x * wa.x + h4.y * wa.y + h4.z * wa.z + h4.w * wa.w
                + r4.x * wb.x + r4.y * wb.y + r4.z * wb.z + r4.w * wb.w;
    }
#pragma unroll
    for (int c = 0; c < 7; c++)
#pragma unroll
        for (int off = 32; off; off >>= 1) part[c] += __shfl_xor(part[c], off);
    if (lane == 0) {
        if (BANK == 0) {
#pragma unroll
            for (int c = 0; c < 7; c++) Plog[(long)n * 7 + c] = part[c];
        } else {
            const int tq = t0 + (n >> 7);
            const int b = n & 127;
            if (tq < lens[b]) {
                float lg[7];
                float mx = -1e30f;
#pragma unroll
                for (int c = 0; c < 7; c++) {
                    lg[c] = Plog[(long)n * 7 + c] + part[c] + ob[c];
                    mx = fmaxf(mx, lg[c]);
                }
                float s = 0.f;
#pragma unroll
                for (int c = 0; c < 7; c++) s += expf(lg[c] - mx);
                const float ls = mx + logf(s);
                float* op = out + (long)(offs[b] + tq) * 7;
#pragma unroll
                for (int c = 0; c < 7; c++) op[c] = lg[c] - ls;
            }
        }
    }
}

// Gate-permuted weights: Wp1[4d+g][k] = w_ih[g*256+d][k];
// Wp2 adds w_hh on k<256.  bp[4d+g] = b_ih[g*256+d]+b_hh[g*256+d].
__global__ void prep_weights_perm(
    const float* __restrict__ w_ih, const float* __restrict__ w_hh,
    const float* __restrict__ b_ih, const float* __restrict__ b_hh,
    float* __restrict__ Wp1, float* __restrict__ Wp2, float* __restrict__ bp)
{
    const long i = (long)blockIdx.x * blockDim.x + threadIdx.x;
    if (i < 1024L * 512) {
        const int mp = (int)(i >> 9), k = (int)(i & 511);
        const int d = mp >> 2, g = mp & 3;
        const int src = g * 256 + d;
        const float v = w_ih[(long)src * 512 + k];
        Wp1[i] = v;
        Wp2[i] = v + ((k < 256) ? w_hh[(long)src * 256 + k] : 0.f);
        if (k == 0) bp[mp] = b_ih[src] + b_hh[src];
    }
}

__global__ void prep_offsets(const int* __restrict__ lens, int* __restrict__ offs)
{
    if (threadIdx.x == 0) {
        int s = 0;
        for (int b = 0; b < 128; b++) {
            offs[b] = s;
            s += lens[b];
        }
        offs[128] = s;
    }
}

extern "C" void kernel_launch(void* const* d_in, const int* in_sizes, int n_in,
                              void* d_out, int out_size, void* d_ws, size_t ws_size,
                              hipStream_t stream)
{
    (void)in_sizes; (void)n_in; (void)out_size; (void)ws_size;
    const float* input    = (const float*)d_in[0];
    const float* speakers = (const float*)d_in[1];
    const int*   lens     = (const int*)d_in[2];
    const float* fc_w     = (const float*)d_in[3];
    const float* fc_b     = (const float*)d_in[4];
    const float* w_ih_s   = (const float*)d_in[5];
    const float* w_hh_s   = (const float*)d_in[6];
    const float* b_ih_s   = (const float*)d_in[7];
    const float* b_hh_s   = (const float*)d_in[8];
    const float* w_ih_p   = (const float*)d_in[9];
    const float* w_hh_p   = (const float*)d_in[10];
    const float* b_ih_p   = (const float*)d_in[11];
    const float* b_hh_p   = (const float*)d_in[12];
    const float* out_w    = (const float*)d_in[13];
    const float* out_b    = (const float*)d_in[14];

    // workspace: ~120 MB total
    float* ws = (float*)d_ws;
    float* QH0 = ws;                    // [NC,256] 16 MB each
    float* QH1 = QH0 + (long)NC * 256;
    float* QR0 = QH1 + (long)NC * 256;
    float* QR1 = QR0 + (long)NC * 256;
    float* Cb  = QR1 + (long)NC * 256;
    float* Eb  = Cb + (long)NC * 256;   // [128][TC][512] 32 MB
    float* Plog = Eb + (long)128 * TC * 512; // [NC,7]
    float* Wp1s = Plog + (long)NC * 7;  // [1024,512] x4
    float* Wp2s = Wp1s + 1024L * 512;
    float* Wp1p = Wp2s + 1024L * 512;
    float* Wp2p = Wp1p + 1024L * 512;
    float* bps  = Wp2p + 1024L * 512;   // [1024] x2
    float* bpp  = bps + 1024;
    int* offs   = (int*)(bpp + 1024);   // [129]

    prep_offsets<<<1, 64, 0, stream>>>(lens, offs);
    prep_weights_perm<<<2048, 256, 0, stream>>>(w_ih_s, w_hh_s, b_ih_s, b_hh_s, Wp1s, Wp2s, bps);
    prep_weights_perm<<<2048, 256, 0, stream>>>(w_ih_p, w_hh_p, b_ih_p, b_hh_p, Wp1p, Wp2p, bpp);

    for (int c = 0; c < 512 / TC; ++c) {
        const int t0 = c * TC;
        for (int bank = 0; bank < 2; ++bank) {
            const float* x   = bank ? speakers : input;
            const float* Wp1 = bank ? Wp1p : Wp1s;
            const float* Wp2 = bank ? Wp2p : Wp2s;
            const float* bp  = bank ? bpp : bps;
            const float* xc  = x + (long)t0 * 128 * 256; // chunk rows of [T,B,D]

            // q0 halves: [NC,512] -> QH0 (cols 0..255), QR0 (cols 256..511); K=256
            gemm_nt<false><<<dim3(NC / BM, 2, 1), 256, 0, stream>>>(
                xc, 256, 0, fc_w, 256, 0, QH0, 256, 0, 256, fc_b);
            gemm_nt<false><<<dim3(NC / BM, 2, 1), 256, 0, stream>>>(
                xc, 256, 0, fc_w + 256L * 256, 256, 0, QR0, 256, 0, 256, fc_b + 256);

            // step 0: gates from [QH0|QR0], h -> QH1
            gemm_gates<true><<<dim3(NC / BM, 8, 1), 256, 0, stream>>>(
                QH0, QR0, Wp1, bp, QH1, Cb);
            // E[b][tc][u] = h . x[u,b,:]
            gemm_nt<false><<<dim3(TC / BM, 4, 128), 256, 0, stream>>>(
                QH1, 128 * 256, 256, x, 128 * 256, 256, Eb, 512, (long)TC * 512, 256, nullptr);
            softmax_kernel<<<128 * TC / 4, 256, 0, stream>>>(Eb, lens);
            // r -> QR1
            gemm_nt<true><<<dim3(TC / BM, 2, 128), 256, 0, stream>>>(
                Eb, 512, (long)TC * 512, x, 128 * 256, 256, QR1, 128 * 256, 256, 512, nullptr);

            // step 1: gates from [QH1|QR1], h -> QH0
            gemm_gates<false><<<dim3(NC / BM, 8, 1), 256, 0, stream>>>(
                QH1, QR1, Wp2, bp, QH0, Cb);
            gemm_nt<false><<<dim3(TC / BM, 4, 128), 256, 0, stream>>>(
                QH0, 128 * 256, 256, x, 128 * 256, 256, Eb, 512, (long)TC * 512, 256, nullptr);
            softmax_kernel<<<128 * TC / 4, 256, 0, stream>>>(Eb, lens);
            gemm_nt<true><<<dim3(TC / BM, 2, 128), 256, 0, stream>>>(
                Eb, 512, (long)TC * 512, x, 128 * 256, 256, QR0, 128 * 256, 256, 512, nullptr);

            // feat = [QH0|QR0]; partial logits (bank 1 finalizes + scatters)
            if (bank == 0)
                plog_kernel<0><<<NC / 4, 256, 0, stream>>>(
                    QH0, QR0, out_w, out_b, lens, offs, t0, Plog, (float*)d_out);
            else
                plog_kernel<1><<<NC / 4, 256, 0, stream>>>(
                    QH0, QR0, out_w, out_b, lens, offs, t0, Plog, (float*)d_out);
        }
    }
}

// Round 9
// 8541.389 us; speedup vs baseline: 3.6799x; 3.6799x over previous
//
#include <hip/hip_runtime.h>
#include <math.h>

#define BM 128
#define BN 128
#define BK 16
#define LDP 132   /* padded leading dim for [BK][...] LDS tiles */
#define TC 128    /* t-chunk */
#define NC (TC * 128) /* rows per chunk = 16384 */

__device__ __forceinline__ float sigf(float x) { return 1.0f / (1.0f + expf(-x)); }

// C[n,m] = sum_k A[n,k]*B[m,k] (+bias[m]).  A is [N,K] row-major (K contiguous).
// B_KM=false: B is [M,K] row-major -> staged transposed.
// B_KM=true : B is [K,M] (M contiguous, row stride ldb) -> staged directly.
template <bool B_KM>
__global__ __launch_bounds__(256, 1) void gemm_nt(
    const float* __restrict__ A, int lda, long sAz,
    const float* __restrict__ B, int ldb, long sBz,
    float* __restrict__ C, int ldc, long sCz,
    int K, const float* __restrict__ bias)
{
    __shared__ alignas(16) float As[2][BK][LDP];
    __shared__ alignas(16) float Bs[2][BK][LDP];
    const int t = threadIdx.x;
    const long z = blockIdx.z;
    A += z * sAz;
    B += z * sBz;
    C += z * sCz;
    const int n0 = blockIdx.x * BM;
    const int m0 = blockIdx.y * BN;
    const int tx = t & 15, ty = t >> 4;
    const int kq = t & 3;
    const int rA = t >> 2;
    const int kb = t >> 5;
    const int cb = t & 31;

    float4 ar[2], br[2];

    auto load_regs = [&](int kt) {
        const int kbase = kt * BK;
        ar[0] = *(const float4*)(A + (long)(n0 + rA) * lda + kbase + kq * 4);
        ar[1] = *(const float4*)(A + (long)(n0 + rA + 64) * lda + kbase + kq * 4);
        if (!B_KM) {
            br[0] = *(const float4*)(B + (long)(m0 + rA) * ldb + kbase + kq * 4);
            br[1] = *(const float4*)(B + (long)(m0 + rA + 64) * ldb + kbase + kq * 4);
        } else {
            br[0] = *(const float4*)(B + (long)(kbase + kb) * ldb + m0 + cb * 4);
            br[1] = *(const float4*)(B + (long)(kbase + kb + 8) * ldb + m0 + cb * 4);
        }
    };
    auto store_lds = [&](int buf) {
        As[buf][kq * 4 + 0][rA] = ar[0].x;
        As[buf][kq * 4 + 1][rA] = ar[0].y;
        As[buf][kq * 4 + 2][rA] = ar[0].z;
        As[buf][kq * 4 + 3][rA] = ar[0].w;
        As[buf][kq * 4 + 0][rA + 64] = ar[1].x;
        As[buf][kq * 4 + 1][rA + 64] = ar[1].y;
        As[buf][kq * 4 + 2][rA + 64] = ar[1].z;
        As[buf][kq * 4 + 3][rA + 64] = ar[1].w;
        if (!B_KM) {
            Bs[buf][kq * 4 + 0][rA] = br[0].x;
            Bs[buf][kq * 4 + 1][rA] = br[0].y;
            Bs[buf][kq * 4 + 2][rA] = br[0].z;
            Bs[buf][kq * 4 + 3][rA] = br[0].w;
            Bs[buf][kq * 4 + 0][rA + 64] = br[1].x;
            Bs[buf][kq * 4 + 1][rA + 64] = br[1].y;
            Bs[buf][kq * 4 + 2][rA + 64] = br[1].z;
            Bs[buf][kq * 4 + 3][rA + 64] = br[1].w;
        } else {
            *(float4*)&Bs[buf][kb][cb * 4] = br[0];
            *(float4*)&Bs[buf][kb + 8][cb * 4] = br[1];
        }
    };

    float acc[8][8];
#pragma unroll
    for (int i = 0; i < 8; i++)
#pragma unroll
        for (int j = 0; j < 8; j++) acc[i][j] = 0.f;

    load_regs(0);
    store_lds(0);
    const int nkt = K / BK;
    for (int kt = 0; kt < nkt; ++kt) {
        __syncthreads();
        const int cur = kt & 1;
        if (kt + 1 < nkt) load_regs(kt + 1);
#pragma unroll
        for (int k = 0; k < BK; ++k) {
            float4 a0 = *(const float4*)&As[cur][k][ty * 4];
            float4 a1 = *(const float4*)&As[cur][k][ty * 4 + 64];
            float4 b0 = *(const float4*)&Bs[cur][k][tx * 4];
            float4 b1 = *(const float4*)&Bs[cur][k][tx * 4 + 64];
            float av[8] = {a0.x, a0.y, a0.z, a0.w, a1.x, a1.y, a1.z, a1.w};
            float bv[8] = {b0.x, b0.y, b0.z, b0.w, b1.x, b1.y, b1.z, b1.w};
#pragma unroll
            for (int i = 0; i < 8; i++)
#pragma unroll
                for (int j = 0; j < 8; j++)
                    acc[i][j] = fmaf(av[i], bv[j], acc[i][j]);
        }
        if (kt + 1 < nkt) store_lds((kt + 1) & 1);
    }

    float bv0[8];
#pragma unroll
    for (int j = 0; j < 8; j++)
        bv0[j] = bias ? bias[m0 + tx * 4 + (j & 3) + (j >> 2) * 64] : 0.f;

#pragma unroll
    for (int i = 0; i < 8; i++) {
        const long row = n0 + ty * 4 + (i & 3) + (i >> 2) * 64;
        float* cp = C + row * (long)ldc + m0;
        float4 v;
        v.x = acc[i][0] + bv0[0];
        v.y = acc[i][1] + bv0[1];
        v.z = acc[i][2] + bv0[2];
        v.w = acc[i][3] + bv0[3];
        *(float4*)(cp + tx * 4) = v;
        v.x = acc[i][4] + bv0[4];
        v.y = acc[i][5] + bv0[5];
        v.z = acc[i][6] + bv0[6];
        v.w = acc[i][7] + bv0[7];
        *(float4*)(cp + tx * 4 + 64) = v;
    }
}

// Fused gates GEMM + LSTM cell.  A = [Ah | Ar] each [NC,256] (K=512 split at 256).
// W is gate-permuted [1024,512] (row 4d+g = gate g of channel d), bp permuted bias.
// Epilogue: c_new = sig(f)*c_old + sig(i)*tanh(g); h = sig(o)*tanh(c_new).
// h -> Hout[n,ch], c_new -> Cbuf[n,ch].  Each (n,ch) touched by exactly one thread.
template <bool STEP0>
__global__ __launch_bounds__(256, 1) void gemm_gates(
    const float* __restrict__ Ah, const float* __restrict__ Ar,
    const float* __restrict__ W, const float* __restrict__ bp,
    float* __restrict__ Hout, float* __restrict__ Cbuf)
{
    __shared__ alignas(16) float As[2][BK][LDP];
    __shared__ alignas(16) float Bs[2][BK][LDP];
    const int t = threadIdx.x;
    const int n0 = blockIdx.x * BM;
    const int m0 = blockIdx.y * BN;
    const int tx = t & 15, ty = t >> 4;
    const int kq = t & 3;
    const int rA = t >> 2;

    float4 ar[2], br[2];

    auto load_regs = [&](int kt) {
        const int kbase = kt * BK;
        const float* Ak = (kbase < 256) ? Ah : Ar;
        const int kc = (kbase & 255) + kq * 4;
        ar[0] = *(const float4*)(Ak + (long)(n0 + rA) * 256 + kc);
        ar[1] = *(const float4*)(Ak + (long)(n0 + rA + 64) * 256 + kc);
        br[0] = *(const float4*)(W + (long)(m0 + rA) * 512 + kbase + kq * 4);
        br[1] = *(const float4*)(W + (long)(m0 + rA + 64) * 512 + kbase + kq * 4);
    };
    auto store_lds = [&](int buf) {
        As[buf][kq * 4 + 0][rA] = ar[0].x;
        As[buf][kq * 4 + 1][rA] = ar[0].y;
        As[buf][kq * 4 + 2][rA] = ar[0].z;
        As[buf][kq * 4 + 3][rA] = ar[0].w;
        As[buf][kq * 4 + 0][rA + 64] = ar[1].x;
        As[buf][kq * 4 + 1][rA + 64] = ar[1].y;
        As[buf][kq * 4 + 2][rA + 64] = ar[1].z;
        As[buf][kq * 4 + 3][rA + 64] = ar[1].w;
        Bs[buf][kq * 4 + 0][rA] = br[0].x;
        Bs[buf][kq * 4 + 1][rA] = br[0].y;
        Bs[buf][kq * 4 + 2][rA] = br[0].z;
        Bs[buf][kq * 4 + 3][rA] = br[0].w;
        Bs[buf][kq * 4 + 0][rA + 64] = br[1].x;
        Bs[buf][kq * 4 + 1][rA + 64] = br[1].y;
        Bs[buf][kq * 4 + 2][rA + 64] = br[1].z;
        Bs[buf][kq * 4 + 3][rA + 64] = br[1].w;
    };

    float acc[8][8];
#pragma unroll
    for (int i = 0; i < 8; i++)
#pragma unroll
        for (int j = 0; j < 8; j++) acc[i][j] = 0.f;

    load_regs(0);
    store_lds(0);
    const int nkt = 512 / BK;
    for (int kt = 0; kt < nkt; ++kt) {
        __syncthreads();
        const int cur = kt & 1;
        if (kt + 1 < nkt) load_regs(kt + 1);
#pragma unroll
        for (int k = 0; k < BK; ++k) {
            float4 a0 = *(const float4*)&As[cur][k][ty * 4];
            float4 a1 = *(const float4*)&As[cur][k][ty * 4 + 64];
            float4 b0 = *(const float4*)&Bs[cur][k][tx * 4];
            float4 b1 = *(const float4*)&Bs[cur][k][tx * 4 + 64];
            float av[8] = {a0.x, a0.y, a0.z, a0.w, a1.x, a1.y, a1.z, a1.w};
            float bv[8] = {b0.x, b0.y, b0.z, b0.w, b1.x, b1.y, b1.z, b1.w};
#pragma unroll
            for (int i = 0; i < 8; i++)
#pragma unroll
                for (int j = 0; j < 8; j++)
                    acc[i][j] = fmaf(av[i], bv[j], acc[i][j]);
        }
        if (kt + 1 < nkt) store_lds((kt + 1) & 1);
    }

    float bv0[8];
#pragma unroll
    for (int j = 0; j < 8; j++)
        bv0[j] = bp[m0 + tx * 4 + (j & 3) + (j >> 2) * 64];

    const int ch0 = (m0 + tx * 4) >> 2; // channel of acc[.][0..3]; +16 for acc[.][4..7]
#pragma unroll
    for (int i = 0; i < 8; i++) {
        const long n = n0 + ty * 4 + (i & 3) + (i >> 2) * 64;
#pragma unroll
        for (int g2 = 0; g2 < 2; g2++) {
            const float ii = acc[i][g2 * 4 + 0] + bv0[g2 * 4 + 0];
            const float ff = acc[i][g2 * 4 + 1] + bv0[g2 * 4 + 1];
            const float gg = acc[i][g2 * 4 + 2] + bv0[g2 * 4 + 2];
            const float oo = acc[i][g2 * 4 + 3] + bv0[g2 * 4 + 3];
            const int ch = ch0 + 16 * g2;
            float co = STEP0 ? 0.f : Cbuf[n * 256 + ch];
            const float cn = sigf(ff) * co + sigf(ii) * tanhf(gg);
            const float hh = sigf(oo) * tanhf(cn);
            Cbuf[n * 256 + ch] = cn;
            Hout[n * 256 + ch] = hh;
        }
    }
}

// Row softmax over E[b][tc][u] (chunk rows = b*TC+tc), u masked to u<len[b].
__global__ __launch_bounds__(256) void softmax_kernel(
    float* __restrict__ E, const int* __restrict__ lens)
{
    const int row = blockIdx.x * 4 + (threadIdx.x >> 6); // row = b*TC + tc
    const int lane = threadIdx.x & 63;
    const int b = row >> 7; // TC = 128
    const int len = lens[b];
    float* e = E + (long)row * 512;
    float4 v0 = *(const float4*)(e + lane * 4);       // u in [0,256): always valid (len>=256)
    float4 v1 = *(const float4*)(e + 256 + lane * 4); // u in [256,512): mask
    const int u1 = 256 + lane * 4;
    float m = fmaxf(fmaxf(v0.x, v0.y), fmaxf(v0.z, v0.w));
    if (u1 + 0 < len) m = fmaxf(m, v1.x);
    if (u1 + 1 < len) m = fmaxf(m, v1.y);
    if (u1 + 2 < len) m = fmaxf(m, v1.z);
    if (u1 + 3 < len) m = fmaxf(m, v1.w);
#pragma unroll
    for (int off = 32; off; off >>= 1) m = fmaxf(m, __shfl_xor(m, off));
    float4 e0, e1;
    e0.x = expf(v0.x - m);
    e0.y = expf(v0.y - m);
    e0.z = expf(v0.z - m);
    e0.w = expf(v0.w - m);
    e1.x = (u1 + 0 < len) ? expf(v1.x - m) : 0.f;
    e1.y = (u1 + 1 < len) ? expf(v1.y - m) : 0.f;
    e1.z = (u1 + 2 < len) ? expf(v1.z - m) : 0.f;
    e1.w = (u1 + 3 < len) ? expf(v1.w - m) : 0.f;
    float s = e0.x + e0.y + e0.z + e0.w + e1.x + e1.y + e1.z + e1.w;
#pragma unroll
    for (int off = 32; off; off >>= 1) s += __shfl_xor(s, off);
    const float inv = 1.f / s;
    e0.x *= inv; e0.y *= inv; e0.z *= inv; e0.w *= inv;
    e1.x *= inv; e1.y *= inv; e1.z *= inv; e1.w *= inv;
    *(float4*)(e + lane * 4) = e0;
    *(float4*)(e + 256 + lane * 4) = e1;
}

// Partial logits for one bank.  feat = relu([QH|QR]) [NC,512]; ow slice [7, 512].
// BANK==0: Plog[n][c] = dot.  BANK==1: finalize log_softmax(Plog+dot+ob) and
// scatter valid rows conversation-major.
template <int BANK>
__global__ __launch_bounds__(256) void plog_kernel(
    const float* __restrict__ QH, const float* __restrict__ QR,
    const float* __restrict__ ow, const float* __restrict__ ob,
    const int* __restrict__ lens, const int* __restrict__ offs, int t0,
    float* __restrict__ Plog, float* __restrict__ out)
{
    __shared__ alignas(16) float wsh[7][512];
    for (int i = threadIdx.x; i < 7 * 512; i += 256)
        wsh[i >> 9][i & 511] = ow[(i >> 9) * 1024 + BANK * 512 + (i & 511)];
    __syncthreads();
    const int n = blockIdx.x * 4 + (threadIdx.x >> 6); // chunk row = tc*128 + b
    const int lane = threadIdx.x & 63;
    float4 h4 = *(const float4*)(QH + (long)n * 256 + lane * 4);
    float4 r4 = *(const float4*)(QR + (long)n * 256 + lane * 4);
    h4.x = fmaxf(h4.x, 0.f); h4.y = fmaxf(h4.y, 0.f); h4.z = fmaxf(h4.z, 0.f); h4.w = fmaxf(h4.w, 0.f);
    r4.x = fmaxf(r4.x, 0.f); r4.y = fmaxf(r4.y, 0.f); r4.z = fmaxf(r4.z, 0.f); r4.w = fmaxf(r4.w, 0.f);
    float part[7];
#pragma unroll
    for (int c = 0; c < 7; c++) {
        float4 wa = *(const float4*)&wsh[c][lane * 4];
        float4 wb = *(const float4*)&wsh[c][256 + lane * 4];
        part[c] = h4.x * wa.x + h4.y * wa.y + h4.z * wa.z + h4.w * wa.w
                + r4.x * wb.x + r4.y * wb.y + r4.z * wb.z + r4.w * wb.w;
    }
#pragma unroll
    for (int c = 0; c < 7; c++)
#pragma unroll
        for (int off = 32; off; off >>= 1) part[c] += __shfl_xor(part[c], off);
    if (lane == 0) {
        if (BANK == 0) {
#pragma unroll
            for (int c = 0; c < 7; c++) Plog[(long)n * 7 + c] = part[c];
        } else {
            const int tq = t0 + (n >> 7);
            const int b = n & 127;
            if (tq < lens[b]) {
                float lg[7];
                float mx = -1e30f;
#pragma unroll
                for (int c = 0; c < 7; c++) {
                    lg[c] = Plog[(long)n * 7 + c] + part[c] + ob[c];
                    mx = fmaxf(mx, lg[c]);
                }
                float s = 0.f;
#pragma unroll
                for (int c = 0; c < 7; c++) s += expf(lg[c] - mx);
                const float ls = mx + logf(s);
                float* op = out + (long)(offs[b] + tq) * 7;
#pragma unroll
                for (int c = 0; c < 7; c++) op[c] = lg[c] - ls;
            }
        }
    }
}

// Gate-permuted weights: Wp1[4d+g][k] = w_ih[g*256+d][k];
// Wp2 adds w_hh on k<256.  bp[4d+g] = b_ih[g*256+d]+b_hh[g*256+d].
__global__ void prep_weights_perm(
    const float* __restrict__ w_ih, const float* __restrict__ w_hh,
    const float* __restrict__ b_ih, const float* __restrict__ b_hh,
    float* __restrict__ Wp1, float* __restrict__ Wp2, float* __restrict__ bp)
{
    const long i = (long)blockIdx.x * blockDim.x + threadIdx.x;
    if (i < 1024L * 512) {
        const int mp = (int)(i >> 9), k = (int)(i & 511);
        const int d = mp >> 2, g = mp & 3;
        const int src = g * 256 + d;
        const float v = w_ih[(long)src * 512 + k];
        Wp1[i] = v;
        Wp2[i] = v + ((k < 256) ? w_hh[(long)src * 256 + k] : 0.f);
        if (k == 0) bp[mp] = b_ih[src] + b_hh[src];
    }
}

__global__ void prep_offsets(const int* __restrict__ lens, int* __restrict__ offs)
{
    if (threadIdx.x == 0) {
        int s = 0;
        for (int b = 0; b < 128; b++) {
            offs[b] = s;
            s += lens[b];
        }
        offs[128] = s;
    }
}

extern "C" void kernel_launch(void* const* d_in, const int* in_sizes, int n_in,
                              void* d_out, int out_size, void* d_ws, size_t ws_size,
                              hipStream_t stream)
{
    (void)in_sizes; (void)n_in; (void)out_size; (void)ws_size;
    const float* input    = (const float*)d_in[0];
    const float* speakers = (const float*)d_in[1];
    const int*   lens     = (const int*)d_in[2];
    const float* fc_w     = (const float*)d_in[3];
    const float* fc_b     = (const float*)d_in[4];
    const float* w_ih_s   = (const float*)d_in[5];
    const float* w_hh_s   = (const float*)d_in[6];
    const float* b_ih_s   = (const float*)d_in[7];
    const float* b_hh_s   = (const float*)d_in[8];
    const float* w_ih_p   = (const float*)d_in[9];
    const float* w_hh_p   = (const float*)d_in[10];
    const float* b_ih_p   = (const float*)d_in[11];
    const float* b_hh_p   = (const float*)d_in[12];
    const float* out_w    = (const float*)d_in[13];
    const float* out_b    = (const float*)d_in[14];

    // workspace: ~120 MB total
    float* ws = (float*)d_ws;
    float* QH0 = ws;                    // [NC,256] 16 MB each
    float* QH1 = QH0 + (long)NC * 256;
    float* QR0 = QH1 + (long)NC * 256;
    float* QR1 = QR0 + (long)NC * 256;
    float* Cb  = QR1 + (long)NC * 256;
    float* Eb  = Cb + (long)NC * 256;   // [128][TC][512] 32 MB
    float* Plog = Eb + (long)128 * TC * 512; // [NC,7]
    float* Wp1s = Plog + (long)NC * 7;  // [1024,512] x4
    float* Wp2s = Wp1s + 1024L * 512;
    float* Wp1p = Wp2s + 1024L * 512;
    float* Wp2p = Wp1p + 1024L * 512;
    float* bps  = Wp2p + 1024L * 512;   // [1024] x2
    float* bpp  = bps + 1024;
    int* offs   = (int*)(bpp + 1024);   // [129]

    prep_offsets<<<1, 64, 0, stream>>>(lens, offs);
    prep_weights_perm<<<2048, 256, 0, stream>>>(w_ih_s, w_hh_s, b_ih_s, b_hh_s, Wp1s, Wp2s, bps);
    prep_weights_perm<<<2048, 256, 0, stream>>>(w_ih_p, w_hh_p, b_ih_p, b_hh_p, Wp1p, Wp2p, bpp);

    for (int c = 0; c < 512 / TC; ++c) {
        const int t0 = c * TC;
        for (int bank = 0; bank < 2; ++bank) {
            const float* x   = bank ? speakers : input;
            const float* Wp1 = bank ? Wp1p : Wp1s;
            const float* Wp2 = bank ? Wp2p : Wp2s;
            const float* bp  = bank ? bpp : bps;
            const float* xc  = x + (long)t0 * 128 * 256; // chunk rows of [T,B,D]

            // q0 halves: [NC,512] -> QH0 (cols 0..255), QR0 (cols 256..511); K=256
            gemm_nt<false><<<dim3(NC / BM, 2, 1), 256, 0, stream>>>(
                xc, 256, 0, fc_w, 256, 0, QH0, 256, 0, 256, fc_b);
            gemm_nt<false><<<dim3(NC / BM, 2, 1), 256, 0, stream>>>(
                xc, 256, 0, fc_w + 256L * 256, 256, 0, QR0, 256, 0, 256, fc_b + 256);

            // step 0: gates from [QH0|QR0], h -> QH1
            gemm_gates<true><<<dim3(NC / BM, 8, 1), 256, 0, stream>>>(
                QH0, QR0, Wp1, bp, QH1, Cb);
            // E[b][tc][u] = h . x[u,b,:]
            gemm_nt<false><<<dim3(TC / BM, 4, 128), 256, 0, stream>>>(
                QH1, 128 * 256, 256, x, 128 * 256, 256, Eb, 512, (long)TC * 512, 256, nullptr);
            softmax_kernel<<<128 * TC / 4, 256, 0, stream>>>(Eb, lens);
            // r -> QR1
            gemm_nt<true><<<dim3(TC / BM, 2, 128), 256, 0, stream>>>(
                Eb, 512, (long)TC * 512, x, 128 * 256, 256, QR1, 128 * 256, 256, 512, nullptr);

            // step 1: gates from [QH1|QR1], h -> QH0
            gemm_gates<false><<<dim3(NC / BM, 8, 1), 256, 0, stream>>>(
                QH1, QR1, Wp2, bp, QH0, Cb);
            gemm_nt<false><<<dim3(TC / BM, 4, 128), 256, 0, stream>>>(
                QH0, 128 * 256, 256, x, 128 * 256, 256, Eb, 512, (long)TC * 512, 256, nullptr);
            softmax_kernel<<<128 * TC / 4, 256, 0, stream>>>(Eb, lens);
            gemm_nt<true><<<dim3(TC / BM, 2, 128), 256, 0, stream>>>(
                Eb, 512, (long)TC * 512, x, 128 * 256, 256, QR0, 128 * 256, 256, 512, nullptr);

            // feat = [QH0|QR0]; partial logits (bank 1 finalizes + scatters)
            if (bank == 0)
                plog_kernel<0><<<NC / 4, 256, 0, stream>>>(
                    QH0, QR0, out_w, out_b, lens, offs, t0, Plog, (float*)d_out);
            else
                plog_kernel<1><<<NC / 4, 256, 0, stream>>>(
                    QH0, QR0, out_w, out_b, lens, offs, t0, Plog, (float*)d_out);
        }
    }
}

// Round 10
// 5470.529 us; speedup vs baseline: 5.7456x; 1.5613x over previous
//
#include <hip/hip_runtime.h>
#include <math.h>

#define BM 128
#define BN 128
#define BK 16
#define LDP 132   /* padded leading dim for [BK][...] LDS tiles */
#define TC 128    /* t-chunk */
#define NC (TC * 128) /* rows per chunk = 16384 */

typedef __attribute__((ext_vector_type(8))) short bf16x8;
typedef __attribute__((ext_vector_type(4))) float f32x4;

__device__ __forceinline__ float sigf(float x) { return 1.0f / (1.0f + expf(-x)); }
__device__ __forceinline__ unsigned short f2bf(float f) {
    unsigned int u = __float_as_uint(f);
    u += 0x7fffu + ((u >> 16) & 1u);   // round-to-nearest-even
    return (unsigned short)(u >> 16);
}

// ---------------- fp32 GEMM (unchanged, verified @ round 9) ----------------
// C[n,m] = sum_k A[n,k]*B[m,k] (+bias[m]).  A is [N,K] row-major.
// B_KM=false: B is [M,K] row-major -> staged transposed.
// B_KM=true : B is [K,M] (M contiguous, row stride ldb) -> staged directly.
template <bool B_KM>
__global__ __launch_bounds__(256, 1) void gemm_nt(
    const float* __restrict__ A, int lda, long sAz,
    const float* __restrict__ B, int ldb, long sBz,
    float* __restrict__ C, int ldc, long sCz,
    int K, const float* __restrict__ bias)
{
    __shared__ alignas(16) float As[2][BK][LDP];
    __shared__ alignas(16) float Bs[2][BK][LDP];
    const int t = threadIdx.x;
    const long z = blockIdx.z;
    A += z * sAz;
    B += z * sBz;
    C += z * sCz;
    const int n0 = blockIdx.x * BM;
    const int m0 = blockIdx.y * BN;
    const int tx = t & 15, ty = t >> 4;
    const int kq = t & 3;
    const int rA = t >> 2;
    const int kb = t >> 5;
    const int cb = t & 31;

    float4 ar[2], br[2];

    auto load_regs = [&](int kt) {
        const int kbase = kt * BK;
        ar[0] = *(const float4*)(A + (long)(n0 + rA) * lda + kbase + kq * 4);
        ar[1] = *(const float4*)(A + (long)(n0 + rA + 64) * lda + kbase + kq * 4);
        if (!B_KM) {
            br[0] = *(const float4*)(B + (long)(m0 + rA) * ldb + kbase + kq * 4);
            br[1] = *(const float4*)(B + (long)(m0 + rA + 64) * ldb + kbase + kq * 4);
        } else {
            br[0] = *(const float4*)(B + (long)(kbase + kb) * ldb + m0 + cb * 4);
            br[1] = *(const float4*)(B + (long)(kbase + kb + 8) * ldb + m0 + cb * 4);
        }
    };
    auto store_lds = [&](int buf) {
        As[buf][kq * 4 + 0][rA] = ar[0].x;
        As[buf][kq * 4 + 1][rA] = ar[0].y;
        As[buf][kq * 4 + 2][rA] = ar[0].z;
        As[buf][kq * 4 + 3][rA] = ar[0].w;
        As[buf][kq * 4 + 0][rA + 64] = ar[1].x;
        As[buf][kq * 4 + 1][rA + 64] = ar[1].y;
        As[buf][kq * 4 + 2][rA + 64] = ar[1].z;
        As[buf][kq * 4 + 3][rA + 64] = ar[1].w;
        if (!B_KM) {
            Bs[buf][kq * 4 + 0][rA] = br[0].x;
            Bs[buf][kq * 4 + 1][rA] = br[0].y;
            Bs[buf][kq * 4 + 2][rA] = br[0].z;
            Bs[buf][kq * 4 + 3][rA] = br[0].w;
            Bs[buf][kq * 4 + 0][rA + 64] = br[1].x;
            Bs[buf][kq * 4 + 1][rA + 64] = br[1].y;
            Bs[buf][kq * 4 + 2][rA + 64] = br[1].z;
            Bs[buf][kq * 4 + 3][rA + 64] = br[1].w;
        } else {
            *(float4*)&Bs[buf][kb][cb * 4] = br[0];
            *(float4*)&Bs[buf][kb + 8][cb * 4] = br[1];
        }
    };

    float acc[8][8];
#pragma unroll
    for (int i = 0; i < 8; i++)
#pragma unroll
        for (int j = 0; j < 8; j++) acc[i][j] = 0.f;

    load_regs(0);
    store_lds(0);
    const int nkt = K / BK;
    for (int kt = 0; kt < nkt; ++kt) {
        __syncthreads();
        const int cur = kt & 1;
        if (kt + 1 < nkt) load_regs(kt + 1);
#pragma unroll
        for (int k = 0; k < BK; ++k) {
            float4 a0 = *(const float4*)&As[cur][k][ty * 4];
            float4 a1 = *(const float4*)&As[cur][k][ty * 4 + 64];
            float4 b0 = *(const float4*)&Bs[cur][k][tx * 4];
            float4 b1 = *(const float4*)&Bs[cur][k][tx * 4 + 64];
            float av[8] = {a0.x, a0.y, a0.z, a0.w, a1.x, a1.y, a1.z, a1.w};
            float bv[8] = {b0.x, b0.y, b0.z, b0.w, b1.x, b1.y, b1.z, b1.w};
#pragma unroll
            for (int i = 0; i < 8; i++)
#pragma unroll
                for (int j = 0; j < 8; j++)
                    acc[i][j] = fmaf(av[i], bv[j], acc[i][j]);
        }
        if (kt + 1 < nkt) store_lds((kt + 1) & 1);
    }

    float bv0[8];
#pragma unroll
    for (int j = 0; j < 8; j++)
        bv0[j] = bias ? bias[m0 + tx * 4 + (j & 3) + (j >> 2) * 64] : 0.f;

#pragma unroll
    for (int i = 0; i < 8; i++) {
        const long row = n0 + ty * 4 + (i & 3) + (i >> 2) * 64;
        float* cp = C + row * (long)ldc + m0;
        float4 v;
        v.x = acc[i][0] + bv0[0];
        v.y = acc[i][1] + bv0[1];
        v.z = acc[i][2] + bv0[2];
        v.w = acc[i][3] + bv0[3];
        *(float4*)(cp + tx * 4) = v;
        v.x = acc[i][4] + bv0[4];
        v.y = acc[i][5] + bv0[5];
        v.z = acc[i][6] + bv0[6];
        v.w = acc[i][7] + bv0[7];
        *(float4*)(cp + tx * 4 + 64) = v;
    }
}

// ---------------- convert [QH|QR] fp32 -> Abf bf16 [NC][512] ----------------
__global__ __launch_bounds__(256) void convert_bf16(
    const float* __restrict__ QH, const float* __restrict__ QR,
    unsigned short* __restrict__ Abf)
{
    const long i = (long)blockIdx.x * 256 + threadIdx.x; // NC*64 groups of 8
    const long n = i >> 6;
    const int k8 = (int)(i & 63) << 3;
    const float* src = (k8 < 256) ? (QH + n * 256 + k8) : (QR + n * 256 + (k8 - 256));
    float4 f0 = *(const float4*)(src);
    float4 f1 = *(const float4*)(src + 4);
    unsigned short o[8];
    o[0] = f2bf(f0.x); o[1] = f2bf(f0.y); o[2] = f2bf(f0.z); o[3] = f2bf(f0.w);
    o[4] = f2bf(f1.x); o[5] = f2bf(f1.y); o[6] = f2bf(f1.z); o[7] = f2bf(f1.w);
    *(uint4*)(Abf + n * 512 + k8) = *(const uint4*)o;
}

// ---------------- bf16 MFMA gates GEMM + fused LSTM cell ----------------
// A: Abf [NC][512] bf16.  W: Wb [1024][512] bf16, rows permuted
//   mp = 64*mblk + 16*gate + c  ->  orig row = gate*256 + (16*mblk + c).
// bpn: fp32 bias, same permutation.  Output: H[n][ch] fp32, Cb[n][ch] fp32,
//   ch = 16*mblk + c.  D-layout (m89): col=lane&15, row=(lane>>4)*4+reg.
__global__ __launch_bounds__(256, 1) void gates_mfma(
    const unsigned short* __restrict__ Abf, const unsigned short* __restrict__ Wb,
    const float* __restrict__ bpn, float* __restrict__ H, float* __restrict__ Cbuf,
    int step0)
{
    __shared__ alignas(16) unsigned short As[128 * 64];  // 16 KB, XOR-swizzled 16B chunks
    __shared__ alignas(16) unsigned short Bs[128 * 64];
    const int t = threadIdx.x;
    const int n0 = blockIdx.x * 128;
    const int m0 = blockIdx.y * 128;

    const int srow = t >> 1;        // staging row 0..127
    const int shalf = t & 1;        // 32-col half
    const int w = t >> 6, l = t & 63;
    const int wrow = (w & 1) << 6, wcol = (w >> 1) << 6;
    const int fr = l & 15, fg = l >> 4;

    f32x4 acc[4][4];
#pragma unroll
    for (int i = 0; i < 4; i++)
#pragma unroll
        for (int j = 0; j < 4; j++) acc[i][j] = (f32x4){0.f, 0.f, 0.f, 0.f};

    for (int kt = 0; kt < 8; ++kt) {   // K = 512, BK = 64
        const unsigned short* Ag = Abf + (long)(n0 + srow) * 512 + kt * 64 + shalf * 32;
        const unsigned short* Bg = Wb + (long)(m0 + srow) * 512 + kt * 64 + shalf * 32;
        uint4 av[4], bv[4];
#pragma unroll
        for (int j = 0; j < 4; j++) {
            av[j] = *(const uint4*)(Ag + j * 8);
            bv[j] = *(const uint4*)(Bg + j * 8);
        }
        __syncthreads();   // previous tile's ds_reads complete
#pragma unroll
        for (int j = 0; j < 4; j++) {
            const int pc = (shalf * 4 + j) ^ (srow & 7);
            *(uint4*)&As[(srow * 8 + pc) * 8] = av[j];
            *(uint4*)&Bs[(srow * 8 + pc) * 8] = bv[j];
        }
        __syncthreads();   // staging visible
#pragma unroll
        for (int ks = 0; ks < 2; ++ks) {
            bf16x8 af[4], bfr[4];
            const int cb = ks * 4 + fg;
#pragma unroll
            for (int i = 0; i < 4; i++) {
                const int arow = wrow + i * 16 + fr;
                af[i] = *(const bf16x8*)&As[(arow * 8 + (cb ^ (arow & 7))) * 8];
                const int brow = wcol + i * 16 + fr;
                bfr[i] = *(const bf16x8*)&Bs[(brow * 8 + (cb ^ (brow & 7))) * 8];
            }
#pragma unroll
            for (int i = 0; i < 4; i++)
#pragma unroll
                for (int j = 0; j < 4; j++)
                    acc[i][j] = __builtin_amdgcn_mfma_f32_16x16x32_bf16(
                        af[i], bfr[j], acc[i][j], 0, 0, 0);
        }
    }

    // epilogue: col tiles j = gate index (via W permutation)
    const int mblk = (m0 + wcol) >> 6;         // 0..15
    const int ch = (mblk << 4) + fr;           // channel 0..255
    float bvv[4];
#pragma unroll
    for (int g = 0; g < 4; g++)
        bvv[g] = bpn[(mblk << 6) + (g << 4) + fr];
#pragma unroll
    for (int i = 0; i < 4; i++) {
#pragma unroll
        for (int v = 0; v < 4; v++) {
            const long n = n0 + wrow + i * 16 + fg * 4 + v;
            const float ii = acc[i][0][v] + bvv[0];
            const float ff = acc[i][1][v] + bvv[1];
            const float gg = acc[i][2][v] + bvv[2];
            const float oo = acc[i][3][v] + bvv[3];
            const float co = step0 ? 0.f : Cbuf[n * 256 + ch];
            const float cn = sigf(ff) * co + sigf(ii) * tanhf(gg);
            const float hh = sigf(oo) * tanhf(cn);
            Cbuf[n * 256 + ch] = cn;
            H[n * 256 + ch] = hh;
        }
    }
}

// Row softmax over E[b][tc][u] (chunk rows = b*TC+tc), u masked to u<len[b].
__global__ __launch_bounds__(256) void softmax_kernel(
    float* __restrict__ E, const int* __restrict__ lens)
{
    const int row = blockIdx.x * 4 + (threadIdx.x >> 6); // row = b*TC + tc
    const int lane = threadIdx.x & 63;
    const int b = row >> 7; // TC = 128
    const int len = lens[b];
    float* e = E + (long)row * 512;
    float4 v0 = *(const float4*)(e + lane * 4);       // u in [0,256): always valid (len>=256)
    float4 v1 = *(const float4*)(e + 256 + lane * 4); // u in [256,512): mask
    const int u1 = 256 + lane * 4;
    float m = fmaxf(fmaxf(v0.x, v0.y), fmaxf(v0.z, v0.w));
    if (u1 + 0 < len) m = fmaxf(m, v1.x);
    if (u1 + 1 < len) m = fmaxf(m, v1.y);
    if (u1 + 2 < len) m = fmaxf(m, v1.z);
    if (u1 + 3 < len) m = fmaxf(m, v1.w);
#pragma unroll
    for (int off = 32; off; off >>= 1) m = fmaxf(m, __shfl_xor(m, off));
    float4 e0, e1;
    e0.x = expf(v0.x - m);
    e0.y = expf(v0.y - m);
    e0.z = expf(v0.z - m);
    e0.w = expf(v0.w - m);
    e1.x = (u1 + 0 < len) ? expf(v1.x - m) : 0.f;
    e1.y = (u1 + 1 < len) ? expf(v1.y - m) : 0.f;
    e1.z = (u1 + 2 < len) ? expf(v1.z - m) : 0.f;
    e1.w = (u1 + 3 < len) ? expf(v1.w - m) : 0.f;
    float s = e0.x + e0.y + e0.z + e0.w + e1.x + e1.y + e1.z + e1.w;
#pragma unroll
    for (int off = 32; off; off >>= 1) s += __shfl_xor(s, off);
    const float inv = 1.f / s;
    e0.x *= inv; e0.y *= inv; e0.z *= inv; e0.w *= inv;
    e1.x *= inv; e1.y *= inv; e1.z *= inv; e1.w *= inv;
    *(float4*)(e + lane * 4) = e0;
    *(float4*)(e + 256 + lane * 4) = e1;
}

// Partial logits for one bank.  feat = relu([QH|QR]) [NC,512]; ow slice [7, 512].
// BANK==0: Plog[n][c] = dot.  BANK==1: finalize log_softmax(Plog+dot+ob) and
// scatter valid rows conversation-major.
template <int BANK>
__global__ __launch_bounds__(256) void plog_kernel(
    const float* __restrict__ QH, const float* __restrict__ QR,
    const float* __restrict__ ow, const float* __restrict__ ob,
    const int* __restrict__ lens, const int* __restrict__ offs, int t0,
    float* __restrict__ Plog, float* __restrict__ out)
{
    __shared__ alignas(16) float wsh[7][512];
    for (int i = threadIdx.x; i < 7 * 512; i += 256)
        wsh[i >> 9][i & 511] = ow[(i >> 9) * 1024 + BANK * 512 + (i & 511)];
    __syncthreads();
    const int n = blockIdx.x * 4 + (threadIdx.x >> 6); // chunk row = tc*128 + b
    const int lane = threadIdx.x & 63;
    float4 h4 = *(const float4*)(QH + (long)n * 256 + lane * 4);
    float4 r4 = *(const float4*)(QR + (long)n * 256 + lane * 4);
    h4.x = fmaxf(h4.x, 0.f); h4.y = fmaxf(h4.y, 0.f); h4.z = fmaxf(h4.z, 0.f); h4.w = fmaxf(h4.w, 0.f);
    r4.x = fmaxf(r4.x, 0.f); r4.y = fmaxf(r4.y, 0.f); r4.z = fmaxf(r4.z, 0.f); r4.w = fmaxf(r4.w, 0.f);
    float part[7];
#pragma unroll
    for (int c = 0; c < 7; c++) {
        float4 wa = *(const float4*)&wsh[c][lane * 4];
        float4 wb = *(const float4*)&wsh[c][256 + lane * 4];
        part[c] = h4.x * wa.x + h4.y * wa.y + h4.z * wa.z + h4.w * wa.w
                + r4.x * wb.x + r4.y * wb.y + r4.z * wb.z + r4.w * wb.w;
    }
#pragma unroll
    for (int c = 0; c < 7; c++)
#pragma unroll
        for (int off = 32; off; off >>= 1) part[c] += __shfl_xor(part[c], off);
    if (lane == 0) {
        if (BANK == 0) {
#pragma unroll
            for (int c = 0; c < 7; c++) Plog[(long)n * 7 + c] = part[c];
        } else {
            const int tq = t0 + (n >> 7);
            const int b = n & 127;
            if (tq < lens[b]) {
                float lg[7];
                float mx = -1e30f;
#pragma unroll
                for (int c = 0; c < 7; c++) {
                    lg[c] = Plog[(long)n * 7 + c] + part[c] + ob[c];
                    mx = fmaxf(mx, lg[c]);
                }
                float s = 0.f;
#pragma unroll
                for (int c = 0; c < 7; c++) s += expf(lg[c] - mx);
                const float ls = mx + logf(s);
                float* op = out + (long)(offs[b] + tq) * 7;
#pragma unroll
                for (int c = 0; c < 7; c++) op[c] = lg[c] - ls;
            }
        }
    }
}

// Weights -> bf16, MFMA permutation: Wb[mp][k], mp = 64*mblk+16*g+c
// orig row = g*256 + (16*mblk + c).  Wb1 = w_ih; Wb2 = w_ih + w_hh (k<256).
// bpn[mp] = b_ih + b_hh (fp32).
__global__ void prep_w(
    const float* __restrict__ w_ih, const float* __restrict__ w_hh,
    const float* __restrict__ b_ih, const float* __restrict__ b_hh,
    unsigned short* __restrict__ Wb1, unsigned short* __restrict__ Wb2,
    float* __restrict__ bpn)
{
    const long i = (long)blockIdx.x * blockDim.x + threadIdx.x;
    if (i < 1024L * 512) {
        const int mp = (int)(i >> 9), k = (int)(i & 511);
        const int g = (mp >> 4) & 3;
        const int d = ((mp >> 6) << 4) | (mp & 15);
        const long src = (long)(g * 256 + d);
        const float v = w_ih[src * 512 + k];
        const float v2 = v + ((k < 256) ? w_hh[src * 256 + k] : 0.f);
        Wb1[i] = f2bf(v);
        Wb2[i] = f2bf(v2);
        if (k == 0) bpn[mp] = b_ih[src] + b_hh[src];
    }
}

__global__ void prep_offsets(const int* __restrict__ lens, int* __restrict__ offs)
{
    if (threadIdx.x == 0) {
        int s = 0;
        for (int b = 0; b < 128; b++) {
            offs[b] = s;
            s += lens[b];
        }
        offs[128] = s;
    }
}

extern "C" void kernel_launch(void* const* d_in, const int* in_sizes, int n_in,
                              void* d_out, int out_size, void* d_ws, size_t ws_size,
                              hipStream_t stream)
{
    (void)in_sizes; (void)n_in; (void)out_size; (void)ws_size;
    const float* input    = (const float*)d_in[0];
    const float* speakers = (const float*)d_in[1];
    const int*   lens     = (const int*)d_in[2];
    const float* fc_w     = (const float*)d_in[3];
    const float* fc_b     = (const float*)d_in[4];
    const float* w_ih_s   = (const float*)d_in[5];
    const float* w_hh_s   = (const float*)d_in[6];
    const float* b_ih_s   = (const float*)d_in[7];
    const float* b_hh_s   = (const float*)d_in[8];
    const float* w_ih_p   = (const float*)d_in[9];
    const float* w_hh_p   = (const float*)d_in[10];
    const float* b_ih_p   = (const float*)d_in[11];
    const float* b_hh_p   = (const float*)d_in[12];
    const float* out_w    = (const float*)d_in[13];
    const float* out_b    = (const float*)d_in[14];

    // workspace ~117 MB
    float* ws = (float*)d_ws;
    float* QH0 = ws;                    // [NC,256] fp32, 16 MB each
    float* QH1 = QH0 + (long)NC * 256;
    float* QR0 = QH1 + (long)NC * 256;
    float* QR1 = QR0 + (long)NC * 256;
    float* Cb  = QR1 + (long)NC * 256;
    float* Eb  = Cb + (long)NC * 256;   // [128][TC][512] fp32, 32 MB
    unsigned short* Abf = (unsigned short*)Eb; // bf16 [NC][512], 16 MB, aliases Eb (disjoint liveness)
    float* Plog = Eb + (long)128 * TC * 512;   // [NC,7]
    unsigned short* Wb1s = (unsigned short*)(Plog + (long)NC * 7); // [1024,512] bf16, 1 MB each
    unsigned short* Wb2s = Wb1s + 1024L * 512;
    unsigned short* Wb1p = Wb2s + 1024L * 512;
    unsigned short* Wb2p = Wb1p + 1024L * 512;
    float* bps  = (float*)(Wb2p + 1024L * 512);   // [1024] fp32 x2
    float* bpp  = bps + 1024;
    int* offs   = (int*)(bpp + 1024);   // [129]

    prep_offsets<<<1, 64, 0, stream>>>(lens, offs);
    prep_w<<<2048, 256, 0, stream>>>(w_ih_s, w_hh_s, b_ih_s, b_hh_s, Wb1s, Wb2s, bps);
    prep_w<<<2048, 256, 0, stream>>>(w_ih_p, w_hh_p, b_ih_p, b_hh_p, Wb1p, Wb2p, bpp);

    for (int c = 0; c < 512 / TC; ++c) {
        const int t0 = c * TC;
        for (int bank = 0; bank < 2; ++bank) {
            const float* x   = bank ? speakers : input;
            const unsigned short* Wb1 = bank ? Wb1p : Wb1s;
            const unsigned short* Wb2 = bank ? Wb2p : Wb2s;
            const float* bp  = bank ? bpp : bps;
            const float* xc  = x + (long)t0 * 128 * 256; // chunk rows of [T,B,D]

            // q0 halves: [NC,512] -> QH0 (cols 0..255), QR0 (cols 256..511); K=256
            gemm_nt<false><<<dim3(NC / BM, 2, 1), 256, 0, stream>>>(
                xc, 256, 0, fc_w, 256, 0, QH0, 256, 0, 256, fc_b);
            gemm_nt<false><<<dim3(NC / BM, 2, 1), 256, 0, stream>>>(
                xc, 256, 0, fc_w + 256L * 256, 256, 0, QR0, 256, 0, 256, fc_b + 256);

            // step 0: gates from bf16([QH0|QR0]), h -> QH1
            convert_bf16<<<NC * 64 / 256, 256, 0, stream>>>(QH0, QR0, Abf);
            gates_mfma<<<dim3(NC / 128, 8), 256, 0, stream>>>(Abf, Wb1, bp, QH1, Cb, 1);
            // E[b][tc][u] = h . x[u,b,:]
            gemm_nt<false><<<dim3(TC / BM, 4, 128), 256, 0, stream>>>(
                QH1, 128 * 256, 256, x, 128 * 256, 256, Eb, 512, (long)TC * 512, 256, nullptr);
            softmax_kernel<<<128 * TC / 4, 256, 0, stream>>>(Eb, lens);
            // r -> QR1
            gemm_nt<true><<<dim3(TC / BM, 2, 128), 256, 0, stream>>>(
                Eb, 512, (long)TC * 512, x, 128 * 256, 256, QR1, 128 * 256, 256, 512, nullptr);

            // step 1: gates from bf16([QH1|QR1]), h -> QH0
            convert_bf16<<<NC * 64 / 256, 256, 0, stream>>>(QH1, QR1, Abf);
            gates_mfma<<<dim3(NC / 128, 8), 256, 0, stream>>>(Abf, Wb2, bp, QH0, Cb, 0);
            gemm_nt<false><<<dim3(TC / BM, 4, 128), 256, 0, stream>>>(
                QH0, 128 * 256, 256, x, 128 * 256, 256, Eb, 512, (long)TC * 512, 256, nullptr);
            softmax_kernel<<<128 * TC / 4, 256, 0, stream>>>(Eb, lens);
            gemm_nt<true><<<dim3(TC / BM, 2, 128), 256, 0, stream>>>(
                Eb, 512, (long)TC * 512, x, 128 * 256, 256, QR0, 128 * 256, 256, 512, nullptr);

            // feat = [QH0|QR0]; partial logits (bank 1 finalizes + scatters)
            if (bank == 0)
                plog_kernel<0><<<NC / 4, 256, 0, stream>>>(
                    QH0, QR0, out_w, out_b, lens, offs, t0, Plog, (float*)d_out);
            else
                plog_kernel<1><<<NC / 4, 256, 0, stream>>>(
                    QH0, QR0, out_w, out_b, lens, offs, t0, Plog, (float*)d_out);
        }
    }
}